// Round 2
// baseline (148.643 us; speedup 1.0000x reference)
//
#include <hip/hip_runtime.h>

#define NORG 13
#define NCH  14
#define VOX  (48 * 256 * 256)   // voxels per (batch, channel) plane
#define EPSF 1e-5f
#define GX   78                 // chunks per (b,organ) plane; 26*78 = 2028 blocks

// ws layout: per (b,organ) combo, 16 padded floats (one 64B line each):
//   slot 0 = inter1, 1 = sq1, 2 = inter2, 3 = sq2, 4 = cnt
#define COMBO_STRIDE 16

__device__ __forceinline__ float wave_reduce(float v) {
#pragma unroll
    for (int off = 32; off; off >>= 1) v += __shfl_xor(v, off, 64);
    return v;
}

__global__ __launch_bounds__(256) void dice_partial(
    const float* __restrict__ pred1, const float* __restrict__ pred2,
    const int* __restrict__ tgt, float* __restrict__ acc_out)
{
    const int bo = blockIdx.y;          // 0..25 = b*13 + o
    const int b  = bo / NORG;
    const int o  = bo % NORG;
    const int ch = o + 1;
    const int nv4 = VOX / 4;

    const float4* p1 = (const float4*)(pred1 + ((size_t)b * NCH + ch) * VOX);
    const float4* p2 = (const float4*)(pred2 + ((size_t)b * NCH + ch) * VOX);
    const int4*   tb = (const int4*)(tgt + (size_t)b * VOX);

    // contiguous chunk per block -> 3 sequential streams
    const int chunk = (nv4 + gridDim.x - 1) / gridDim.x;
    const int beg   = blockIdx.x * chunk;
    const int end   = min(beg + chunk, nv4);

    float i1 = 0.f, s1 = 0.f, i2 = 0.f, s2 = 0.f, cn = 0.f;

    for (int v = beg + threadIdx.x; v < end; v += 256) {
        const int4   t = tb[v];
        const float4 a = p1[v];
        const float4 c = p2[v];
        const float m0 = (t.x == ch) ? 1.f : 0.f;
        const float m1 = (t.y == ch) ? 1.f : 0.f;
        const float m2 = (t.z == ch) ? 1.f : 0.f;
        const float m3 = (t.w == ch) ? 1.f : 0.f;
        s1 += a.x * a.x + a.y * a.y + a.z * a.z + a.w * a.w;
        s2 += c.x * c.x + c.y * c.y + c.z * c.z + c.w * c.w;
        i1 += m0 * a.x + m1 * a.y + m2 * a.z + m3 * a.w;
        i2 += m0 * c.x + m1 * c.y + m2 * c.z + m3 * c.w;
        cn += (m0 + m1) + (m2 + m3);
    }

    // block reduce: per-wave shuffle tree -> LDS across 4 waves -> 5 atomics
    __shared__ float red[4][5];
    const int lane = threadIdx.x & 63;
    const int wid  = threadIdx.x >> 6;
    float vals[5] = {i1, s1, i2, s2, cn};
#pragma unroll
    for (int s = 0; s < 5; ++s) {
        const float r = wave_reduce(vals[s]);
        if (lane == 0) red[wid][s] = r;
    }
    __syncthreads();
    if (threadIdx.x < 5) {
        const float s = red[0][threadIdx.x] + red[1][threadIdx.x]
                      + red[2][threadIdx.x] + red[3][threadIdx.x];
        atomicAdd(&acc_out[bo * COMBO_STRIDE + threadIdx.x], s);
    }
}

__global__ void dice_final(const float* __restrict__ acc,
                           float* __restrict__ out, int B)
{
    if (threadIdx.x == 0 && blockIdx.x == 0) {
        float total = 0.f;
        for (int b = 0; b < B; ++b) {
            float d1 = 0.f, d2 = 0.f;
            for (int o = 0; o < NORG; ++o) {
                const float* a = acc + (b * NORG + o) * COMBO_STRIDE;
                const float t2 = a[4];
                d1 += 2.f * a[0] / (a[1] + t2 + EPSF);
                d2 += 2.f * a[2] / (a[3] + t2 + EPSF);
            }
            total += 2.f - (d1 + d2) / (float)NORG;
        }
        out[0] = total / (float)B;
    }
}

extern "C" void kernel_launch(void* const* d_in, const int* in_sizes, int n_in,
                              void* d_out, int out_size, void* d_ws, size_t ws_size,
                              hipStream_t stream)
{
    const float* p1  = (const float*)d_in[0];
    const float* p2  = (const float*)d_in[1];
    const int*   tgt = (const int*)d_in[2];
    float*       out = (float*)d_out;
    float*       acc = (float*)d_ws;

    const int B = in_sizes[2] / VOX;   // = 2 for the reference shapes

    // zero the padded accumulator slots every call (ws is poisoned once and
    // never restored between timed replays)
    hipMemsetAsync(d_ws, 0, (size_t)B * NORG * COMBO_STRIDE * sizeof(float), stream);

    dim3 grid(GX, B * NORG);           // 78 x 26 = 2028 blocks, ~8/CU resident
    dice_partial<<<grid, 256, 0, stream>>>(p1, p2, tgt, acc);
    dice_final<<<1, 64, 0, stream>>>(acc, out, B);
}

// Round 3
// 135.579 us; speedup vs baseline: 1.0964x; 1.0964x over previous
//
#include <hip/hip_runtime.h>

#define NORG 13
#define NCH  14
#define VOX  (48 * 256 * 256)   // voxels per (batch, channel) plane
#define EPSF 1e-5f
#define CHUNK 8192              // voxels per block (LDS uchar = 8 KB)
#define NCHUNK (VOX / CHUNK)    // 384 chunks per batch
#define ITER (CHUNK / 4 / 256)  // 8 float4-iterations per pass
#define COMBO_STRIDE 16         // padded ws slots per (b,organ)

__device__ __forceinline__ float wave_reduce(float v) {
#pragma unroll
    for (int off = 32; off; off >>= 1) v += __shfl_xor(v, off, 64);
    return v;
}

__global__ __launch_bounds__(256) void dice_partial(
    const float* __restrict__ pred1, const float* __restrict__ pred2,
    const int* __restrict__ tgt, float* __restrict__ acc_out)
{
    const int b     = blockIdx.y;
    const int chunk = blockIdx.x;
    const size_t v0 = (size_t)chunk * CHUNK;

    __shared__ unsigned char t_lds[CHUNK];   // target chunk, staged ONCE
    __shared__ float acc[NORG * 5];          // block-level accumulators

    if (threadIdx.x < NORG * 5) acc[threadIdx.x] = 0.f;

    // ---- stage target chunk into LDS as uchar (read target exactly once) ----
    const int4* tb = (const int4*)(tgt + (size_t)b * VOX + v0);
    uchar4* tl4 = (uchar4*)t_lds;
#pragma unroll
    for (int i = 0; i < ITER; ++i) {
        const int4 t = tb[i * 256 + threadIdx.x];
        tl4[i * 256 + threadIdx.x] =
            make_uchar4((unsigned char)t.x, (unsigned char)t.y,
                        (unsigned char)t.z, (unsigned char)t.w);
    }
    __syncthreads();

    const uchar4* tl = (const uchar4*)t_lds;
    const int lane = threadIdx.x & 63;

    // ---- 13 channel passes, both stages fused (2 HBM streams per pass) ----
    for (int o = 0; o < NORG; ++o) {
        const int ch = o + 1;
        const float4* p1 = (const float4*)(pred1 + ((size_t)b * NCH + ch) * VOX + v0);
        const float4* p2 = (const float4*)(pred2 + ((size_t)b * NCH + ch) * VOX + v0);

        float i1 = 0.f, s1 = 0.f, i2 = 0.f, s2 = 0.f, cn = 0.f;
#pragma unroll
        for (int i = 0; i < ITER; ++i) {
            const int idx = i * 256 + threadIdx.x;
            const uchar4 t = tl[idx];
            const float4 a = p1[idx];
            const float4 c = p2[idx];
            const float m0 = (t.x == ch) ? 1.f : 0.f;
            const float m1 = (t.y == ch) ? 1.f : 0.f;
            const float m2 = (t.z == ch) ? 1.f : 0.f;
            const float m3 = (t.w == ch) ? 1.f : 0.f;
            s1 += a.x * a.x + a.y * a.y + a.z * a.z + a.w * a.w;
            s2 += c.x * c.x + c.y * c.y + c.z * c.z + c.w * c.w;
            i1 += m0 * a.x + m1 * a.y + m2 * a.z + m3 * a.w;
            i2 += m0 * c.x + m1 * c.y + m2 * c.z + m3 * c.w;
            cn += (m0 + m1) + (m2 + m3);
        }

        // per-wave tree reduce, lane0 of each wave accumulates via LDS atomics
        float vals[5] = {i1, s1, i2, s2, cn};
#pragma unroll
        for (int s = 0; s < 5; ++s) {
            const float r = wave_reduce(vals[s]);
            if (lane == 0) atomicAdd(&acc[o * 5 + s], r);
        }
    }

    __syncthreads();
    // one batch of 65 global atomics per block
    if (threadIdx.x < NORG * 5) {
        const int o = threadIdx.x / 5;
        const int s = threadIdx.x % 5;
        atomicAdd(&acc_out[(b * NORG + o) * COMBO_STRIDE + s], acc[threadIdx.x]);
    }
}

__global__ void dice_final(const float* __restrict__ acc,
                           float* __restrict__ out, int B)
{
    if (threadIdx.x == 0 && blockIdx.x == 0) {
        float total = 0.f;
        for (int b = 0; b < B; ++b) {
            float d1 = 0.f, d2 = 0.f;
            for (int o = 0; o < NORG; ++o) {
                const float* a = acc + (b * NORG + o) * COMBO_STRIDE;
                const float t2 = a[4];
                d1 += 2.f * a[0] / (a[1] + t2 + EPSF);
                d2 += 2.f * a[2] / (a[3] + t2 + EPSF);
            }
            total += 2.f - (d1 + d2) / (float)NORG;
        }
        out[0] = total / (float)B;
    }
}

extern "C" void kernel_launch(void* const* d_in, const int* in_sizes, int n_in,
                              void* d_out, int out_size, void* d_ws, size_t ws_size,
                              hipStream_t stream)
{
    const float* p1  = (const float*)d_in[0];
    const float* p2  = (const float*)d_in[1];
    const int*   tgt = (const int*)d_in[2];
    float*       out = (float*)d_out;
    float*       acc = (float*)d_ws;

    const int B = in_sizes[2] / VOX;   // = 2 for the reference shapes

    // zero the padded accumulator slots (ws poisoned once, never re-zeroed)
    hipMemsetAsync(d_ws, 0, (size_t)B * NORG * COMBO_STRIDE * sizeof(float), stream);

    dim3 grid(NCHUNK, B);              // 384 x 2 = 768 blocks, 3/CU
    dice_partial<<<grid, 256, 0, stream>>>(p1, p2, tgt, acc);
    dice_final<<<1, 64, 0, stream>>>(acc, out, B);
}